// Round 2
// baseline (372.011 us; speedup 1.0000x reference)
//
#include <hip/hip_runtime.h>

#define Bc 16
#define Nc 4096
#define Cc 512
#define Sc 8
#define PERB (Nc*Sc)          // 32768 = per-b space_attn elems
#define WP 516                // LDS pad for 8x512 f32 weight tiles

__device__ __forceinline__ float wave_max(float v){
  #pragma unroll
  for (int o = 32; o; o >>= 1) v = fmaxf(v, __shfl_xor(v, o, 64));
  return v;
}
__device__ __forceinline__ float wave_sum(float v){
  #pragma unroll
  for (int o = 32; o; o >>= 1) v += __shfl_xor(v, o, 64);
  return v;
}

// ---------------- K1: SA[row][s] = dot(x[row,:], w_sum[s,:]) + b_sum[s] ----------------
// grid 2048, block 256. Each wave: 8 rows x 8 s (lane = (rsub<<3)|s), no cross-lane reduce.
__global__ __launch_bounds__(256) void k1_space_attn(
    const float* __restrict__ x, const float* __restrict__ w_sum,
    const float* __restrict__ b_sum, float* __restrict__ SA)
{
  __shared__ float wlds[Sc*WP];
  __shared__ float blds[Sc];
  int t = threadIdx.x;
  for (int i = t; i < Sc*Cc; i += 256) {
    int s = i >> 9, c = i & 511;
    wlds[s*WP + c] = w_sum[i];
  }
  if (t < Sc) blds[t] = b_sum[t];
  __syncthreads();
  int wave = t >> 6, lane = t & 63;
  int s = lane & 7, rsub = lane >> 3;
  long row = (long)blockIdx.x * 32 + wave*8 + rsub;
  const float* xr = x + row * Cc;
  float acc = blds[s];
  #pragma unroll 4
  for (int c = 0; c < Cc; c += 8) {
    float4 x0 = *(const float4*)(xr + c);
    float4 x1 = *(const float4*)(xr + c + 4);
    float4 w0 = *(const float4*)&wlds[s*WP + c];
    float4 w1 = *(const float4*)&wlds[s*WP + c + 4];
    acc = fmaf(x0.x, w0.x, acc);
    acc = fmaf(x0.y, w0.y, acc);
    acc = fmaf(x0.z, w0.z, acc);
    acc = fmaf(x0.w, w0.w, acc);
    acc = fmaf(x1.x, w1.x, acc);
    acc = fmaf(x1.y, w1.y, acc);
    acc = fmaf(x1.z, w1.z, acc);
    acc = fmaf(x1.w, w1.w, acc);
  }
  SA[row*8 + s] = acc;   // lanes write consecutive addresses
}

// ---------------- K2: softmax over n per (b,s); W[b][s][n] = exp(v-m)/l ----------------
// grid 128 (= B*S), block 256. Slice is contiguous: SA + b*PERB + s*N .. +N.
__global__ __launch_bounds__(256) void k2_softmax(
    const float* __restrict__ SA, float* __restrict__ W)
{
  int b = blockIdx.x >> 3, s = blockIdx.x & 7;
  const float* p = SA + (long)b*PERB + s*Nc;
  float* wp = W + (long)b*PERB + s*Nc;
  int t = threadIdx.x, wave = t >> 6, lane = t & 63;
  __shared__ float red[4];
  float v[16];
  float m = -3.4e38f;
  #pragma unroll
  for (int i = 0; i < 16; i++) { v[i] = p[t + 256*i]; m = fmaxf(m, v[i]); }
  m = wave_max(m);
  if (lane == 0) red[wave] = m;
  __syncthreads();
  m = fmaxf(fmaxf(red[0], red[1]), fmaxf(red[2], red[3]));
  __syncthreads();
  float sum = 0.f;
  #pragma unroll
  for (int i = 0; i < 16; i++) { v[i] = __expf(v[i] - m); sum += v[i]; }
  sum = wave_sum(sum);
  if (lane == 0) red[wave] = sum;
  __syncthreads();
  sum = red[0] + red[1] + red[2] + red[3];
  float inv = 1.f / sum;
  #pragma unroll
  for (int i = 0; i < 16; i++) wp[t + 256*i] = v[i] * inv;
}

// ---------------- K3: tokens[b][s][c] = max_n W[b][s][n] * x_flat[b][c*N+n] ----------------
// grid 1024 (= B * C/8), block 256. Wave covers 1024 n; acc[8 c][8 s] per lane.
__global__ __launch_bounds__(256) void k3_tokens(
    const float* __restrict__ x, const float* __restrict__ W, float* __restrict__ TOK)
{
  int b = blockIdx.x >> 6;
  int c0 = (blockIdx.x & 63) * 8;
  int t = threadIdx.x, wave = t >> 6, lane = t & 63;
  const float* Wb = W + (long)b*PERB;
  const float* xb = x + (long)b*Nc*Cc;
  float acc[8][8];
  #pragma unroll
  for (int cc = 0; cc < 8; cc++)
    #pragma unroll
    for (int s = 0; s < 8; s++) acc[cc][s] = -3.4e38f;
  int nbase = wave * 1024 + 2*lane;
  for (int step = 0; step < 8; step++) {
    int n = nbase + step*128;
    float2 wv[8];
    #pragma unroll
    for (int s = 0; s < 8; s++) wv[s] = *(const float2*)(Wb + s*Nc + n);
    #pragma unroll
    for (int cc = 0; cc < 8; cc++) {
      float2 xv = *(const float2*)(xb + (c0+cc)*Nc + n);
      #pragma unroll
      for (int s = 0; s < 8; s++) {
        float p0 = wv[s].x * xv.x, p1 = wv[s].y * xv.y;
        acc[cc][s] = fmaxf(acc[cc][s], fmaxf(p0, p1));
      }
    }
  }
  #pragma unroll
  for (int o = 32; o; o >>= 1) {
    #pragma unroll
    for (int cc = 0; cc < 8; cc++)
      #pragma unroll
      for (int s = 0; s < 8; s++)
        acc[cc][s] = fmaxf(acc[cc][s], __shfl_xor(acc[cc][s], o, 64));
  }
  __shared__ float part[4][64];
  if (lane == 0) {
    #pragma unroll
    for (int cc = 0; cc < 8; cc++)
      #pragma unroll
      for (int s = 0; s < 8; s++) part[wave][cc*8+s] = acc[cc][s];
  }
  __syncthreads();
  if (t < 64) {
    float m = fmaxf(fmaxf(part[0][t], part[1][t]), fmaxf(part[2][t], part[3][t]));
    int cc = t >> 3, s = t & 7;
    TOK[b*4096 + s*Cc + c0 + cc] = m;
  }
}

// ---------------- K4a: QKV[b][s][j] = dot(tokens[b][s][:], w_qkv[j][:]) ----------------
// grid 768 (= B * 1536/32), block 256. lane = (jj<<3)|s like K1.
__global__ __launch_bounds__(256) void k4a_qkv(
    const float* __restrict__ TOK, const float* __restrict__ w_qkv, float* __restrict__ QKV)
{
  int b = blockIdx.x / 48;
  int j0 = (blockIdx.x % 48) * 32;
  __shared__ float tl[Sc*WP];
  int t = threadIdx.x;
  for (int i = t; i < Sc*Cc; i += 256) {
    int s = i >> 9, c = i & 511;
    tl[s*WP + c] = TOK[b*4096 + i];
  }
  __syncthreads();
  int wave = t >> 6, lane = t & 63;
  int s = lane & 7, jj = lane >> 3;
  int j = j0 + wave*8 + jj;
  const float* wr = w_qkv + (long)j * Cc;
  float acc = 0.f;
  #pragma unroll 4
  for (int c = 0; c < Cc; c += 8) {
    float4 w0 = *(const float4*)(wr + c);
    float4 w1 = *(const float4*)(wr + c + 4);
    float4 t0 = *(const float4*)&tl[s*WP + c];
    float4 t1 = *(const float4*)&tl[s*WP + c + 4];
    acc = fmaf(w0.x, t0.x, acc);
    acc = fmaf(w0.y, t0.y, acc);
    acc = fmaf(w0.z, t0.z, acc);
    acc = fmaf(w0.w, t0.w, acc);
    acc = fmaf(w1.x, t1.x, acc);
    acc = fmaf(w1.y, t1.y, acc);
    acc = fmaf(w1.z, t1.z, acc);
    acc = fmaf(w1.w, t1.w, acc);
  }
  QKV[b*12288 + s*1536 + j] = acc;
}

// ---------------- K4b: tiny attention (S=8) + cross mix -> ASP2[b][s][c] ----------------
// grid 16 (= B), block 256.
__global__ __launch_bounds__(256) void k4b_attn(
    const float* __restrict__ QKV, const float* __restrict__ w_cross, float* __restrict__ ASP2)
{
  int b = blockIdx.x, t = threadIdx.x;
  __shared__ float qkv[12288];
  __shared__ float attn[512];   // [h][i][j]
  __shared__ float asp[4096];   // [i][c]
  __shared__ float wc[64];
  for (int i = t*4; i < 12288; i += 1024)
    *(float4*)&qkv[i] = *(const float4*)&QKV[b*12288 + i];
  if (t < 64) wc[t] = w_cross[t];
  __syncthreads();
  for (int idx = t; idx < 512; idx += 256) {
    int h = idx >> 6, i = (idx >> 3) & 7, j = idx & 7;
    float sc = 0.f;
    #pragma unroll 8
    for (int d = 0; d < 64; d++)
      sc = fmaf(qkv[i*1536 + h*64 + d], qkv[j*1536 + 512 + h*64 + d], sc);
    attn[idx] = sc * 0.125f;
  }
  __syncthreads();
  if (t < 64) {
    int base = t * 8;  // row (h,i)
    float m = -3.4e38f;
    #pragma unroll
    for (int j = 0; j < 8; j++) m = fmaxf(m, attn[base+j]);
    float sum = 0.f;
    #pragma unroll
    for (int j = 0; j < 8; j++) { float e = __expf(attn[base+j] - m); attn[base+j] = e; sum += e; }
    float inv = 1.f / sum;
    #pragma unroll
    for (int j = 0; j < 8; j++) attn[base+j] *= inv;
  }
  __syncthreads();
  for (int idx = t; idx < 4096; idx += 256) {
    int i = idx >> 9, c = idx & 511, h = c >> 6;
    float a = 0.f;
    #pragma unroll
    for (int j = 0; j < 8; j++)
      a = fmaf(attn[h*64 + i*8 + j], qkv[j*1536 + 1024 + c], a);
    asp[idx] = a;
  }
  __syncthreads();
  for (int idx = t; idx < 4096; idx += 256) {
    int s = idx >> 9, c = idx & 511;
    float a = 0.f;
    #pragma unroll
    for (int j = 0; j < 8; j++)
      a = fmaf(wc[s*8 + j], asp[j*512 + c], a);
    ASP2[b*4096 + idx] = a;
  }
}

// ---------------- K5: out[b,n,c] = LN_c(sum_s sa[b,n,s]*ASP2[b,s,c]) + x[b,n,c] ----------------
// grid 512 (= B * N/128), block 256. Lane owns c in [8l, 8l+8); asp2 tile cached in regs.
__global__ __launch_bounds__(256) void k5_out(
    const float* __restrict__ SA, const float* __restrict__ ASP2,
    const float* __restrict__ x, const float* __restrict__ gamma,
    const float* __restrict__ beta, float* __restrict__ out)
{
  int b = blockIdx.x >> 5;
  int n0 = (blockIdx.x & 31) * 128;
  int t = threadIdx.x, wave = t >> 6, lane = t & 63;
  int c0 = lane * 8;
  float a2[8][8];
  #pragma unroll
  for (int s = 0; s < 8; s++) {
    float4 p0 = *(const float4*)(ASP2 + b*4096 + s*Cc + c0);
    float4 p1 = *(const float4*)(ASP2 + b*4096 + s*Cc + c0 + 4);
    a2[s][0]=p0.x; a2[s][1]=p0.y; a2[s][2]=p0.z; a2[s][3]=p0.w;
    a2[s][4]=p1.x; a2[s][5]=p1.y; a2[s][6]=p1.z; a2[s][7]=p1.w;
  }
  float g[8], be[8];
  {
    float4 g0 = *(const float4*)(gamma + c0);
    float4 g1 = *(const float4*)(gamma + c0 + 4);
    float4 b0 = *(const float4*)(beta + c0);
    float4 b1 = *(const float4*)(beta + c0 + 4);
    g[0]=g0.x; g[1]=g0.y; g[2]=g0.z; g[3]=g0.w;
    g[4]=g1.x; g[5]=g1.y; g[6]=g1.z; g[7]=g1.w;
    be[0]=b0.x; be[1]=b0.y; be[2]=b0.z; be[3]=b0.w;
    be[4]=b1.x; be[5]=b1.y; be[6]=b1.z; be[7]=b1.w;
  }
  __shared__ float salds[128*8];  // [n_local][s]
  {
    int s = t >> 5, q = t & 31;
    float4 v = *(const float4*)(SA + (long)b*PERB + s*Nc + n0 + q*4);
    salds[(q*4+0)*8 + s] = v.x;
    salds[(q*4+1)*8 + s] = v.y;
    salds[(q*4+2)*8 + s] = v.z;
    salds[(q*4+3)*8 + s] = v.w;
  }
  __syncthreads();
  const float inv512 = 1.f/512.f;
  for (int nl = wave*32; nl < wave*32 + 32; nl++) {
    int n = n0 + nl;
    float sa8[8];
    #pragma unroll
    for (int s = 0; s < 8; s++) sa8[s] = salds[nl*8 + s];
    float o[8];
    #pragma unroll
    for (int i = 0; i < 8; i++) {
      float v = 0.f;
      #pragma unroll
      for (int s = 0; s < 8; s++) v = fmaf(sa8[s], a2[s][i], v);
      o[i] = v;
    }
    float sum = 0.f, sq = 0.f;
    #pragma unroll
    for (int i = 0; i < 8; i++) { sum += o[i]; sq = fmaf(o[i], o[i], sq); }
    #pragma unroll
    for (int off = 32; off; off >>= 1) {
      sum += __shfl_xor(sum, off, 64);
      sq  += __shfl_xor(sq,  off, 64);
    }
    float mu = sum * inv512;
    float var = sq * inv512 - mu*mu;
    float r = rsqrtf(var + 1e-5f);
    long row = (long)b*Nc + n;
    float4 x0 = *(const float4*)(x + row*Cc + c0);
    float4 x1 = *(const float4*)(x + row*Cc + c0 + 4);
    float xf[8];
    xf[0]=x0.x; xf[1]=x0.y; xf[2]=x0.z; xf[3]=x0.w;
    xf[4]=x1.x; xf[5]=x1.y; xf[6]=x1.z; xf[7]=x1.w;
    float4 o0, o1;
    o0.x = (o[0] - mu) * r * g[0] + be[0] + xf[0];
    o0.y = (o[1] - mu) * r * g[1] + be[1] + xf[1];
    o0.z = (o[2] - mu) * r * g[2] + be[2] + xf[2];
    o0.w = (o[3] - mu) * r * g[3] + be[3] + xf[3];
    o1.x = (o[4] - mu) * r * g[4] + be[4] + xf[4];
    o1.y = (o[5] - mu) * r * g[5] + be[5] + xf[5];
    o1.z = (o[6] - mu) * r * g[6] + be[6] + xf[6];
    o1.w = (o[7] - mu) * r * g[7] + be[7] + xf[7];
    *(float4*)(out + row*Cc + c0) = o0;
    *(float4*)(out + row*Cc + c0 + 4) = o1;
  }
}

extern "C" void kernel_launch(void* const* d_in, const int* in_sizes, int n_in,
                              void* d_out, int out_size, void* d_ws, size_t ws_size,
                              hipStream_t stream) {
  const float* x       = (const float*)d_in[0];
  const float* w_sum   = (const float*)d_in[1];
  const float* b_sum   = (const float*)d_in[2];
  const float* w_qkv   = (const float*)d_in[3];
  const float* w_cross = (const float*)d_in[4];
  const float* gamma   = (const float*)d_in[5];
  const float* beta    = (const float*)d_in[6];
  float* out = (float*)d_out;
  float* ws = (float*)d_ws;
  float* SA   = ws;                 // 524288 f32
  float* W    = ws + 524288;        // 524288 f32
  float* TOK  = ws + 1048576;       // 65536 f32
  float* QKV  = ws + 1114112;       // 196608 f32
  float* ASP2 = ws + 1310720;       // 65536 f32

  k1_space_attn<<<2048, 256, 0, stream>>>(x, w_sum, b_sum, SA);
  k2_softmax<<<128, 256, 0, stream>>>(SA, W);
  k3_tokens<<<1024, 256, 0, stream>>>(x, W, TOK);
  k4a_qkv<<<768, 256, 0, stream>>>(TOK, w_qkv, QKV);
  k4b_attn<<<16, 256, 0, stream>>>(QKV, w_cross, ASP2);
  k5_out<<<512, 256, 0, stream>>>(SA, ASP2, x, gamma, beta, out);
}

// Round 3
// 346.623 us; speedup vs baseline: 1.0732x; 1.0732x over previous
//
#include <hip/hip_runtime.h>

#define Bc 16
#define Nc 4096
#define Cc 512
#define Sc 8
#define PERB (Nc*Sc)          // 32768 = per-b space_attn elems
#define WP 516                // LDS pad for 8x512 f32 weight tiles

__device__ __forceinline__ float wave_max(float v){
  #pragma unroll
  for (int o = 32; o; o >>= 1) v = fmaxf(v, __shfl_xor(v, o, 64));
  return v;
}
__device__ __forceinline__ float wave_sum(float v){
  #pragma unroll
  for (int o = 32; o; o >>= 1) v += __shfl_xor(v, o, 64);
  return v;
}

// ---------------- K1: SA[row][s] = dot(x[row,:], w_sum[s,:]) + b_sum[s] ----------------
// grid 2048, block 256. Each wave: 8 rows x 8 s (lane = (rsub<<3)|s), no cross-lane reduce.
__global__ __launch_bounds__(256) void k1_space_attn(
    const float* __restrict__ x, const float* __restrict__ w_sum,
    const float* __restrict__ b_sum, float* __restrict__ SA)
{
  __shared__ float wlds[Sc*WP];
  __shared__ float blds[Sc];
  int t = threadIdx.x;
  for (int i = t; i < Sc*Cc; i += 256) {
    int s = i >> 9, c = i & 511;
    wlds[s*WP + c] = w_sum[i];
  }
  if (t < Sc) blds[t] = b_sum[t];
  __syncthreads();
  int wave = t >> 6, lane = t & 63;
  int s = lane & 7, rsub = lane >> 3;
  long row = (long)blockIdx.x * 32 + wave*8 + rsub;
  const float* xr = x + row * Cc;
  float acc = blds[s];
  #pragma unroll 4
  for (int c = 0; c < Cc; c += 8) {
    float4 x0 = *(const float4*)(xr + c);
    float4 x1 = *(const float4*)(xr + c + 4);
    float4 w0 = *(const float4*)&wlds[s*WP + c];
    float4 w1 = *(const float4*)&wlds[s*WP + c + 4];
    acc = fmaf(x0.x, w0.x, acc);
    acc = fmaf(x0.y, w0.y, acc);
    acc = fmaf(x0.z, w0.z, acc);
    acc = fmaf(x0.w, w0.w, acc);
    acc = fmaf(x1.x, w1.x, acc);
    acc = fmaf(x1.y, w1.y, acc);
    acc = fmaf(x1.z, w1.z, acc);
    acc = fmaf(x1.w, w1.w, acc);
  }
  SA[row*8 + s] = acc;   // lanes write consecutive addresses
}

// ---------------- K2: softmax over n per (b,s); W[b][s][n] = exp(v-m)/l ----------------
// grid 128 (= B*S), block 256. Slice is contiguous: SA + b*PERB + s*N .. +N.
__global__ __launch_bounds__(256) void k2_softmax(
    const float* __restrict__ SA, float* __restrict__ W)
{
  int b = blockIdx.x >> 3, s = blockIdx.x & 7;
  const float* p = SA + (long)b*PERB + s*Nc;
  float* wp = W + (long)b*PERB + s*Nc;
  int t = threadIdx.x, wave = t >> 6, lane = t & 63;
  __shared__ float red[4];
  float v[16];
  float m = -3.4e38f;
  #pragma unroll
  for (int i = 0; i < 16; i++) { v[i] = p[t + 256*i]; m = fmaxf(m, v[i]); }
  m = wave_max(m);
  if (lane == 0) red[wave] = m;
  __syncthreads();
  m = fmaxf(fmaxf(red[0], red[1]), fmaxf(red[2], red[3]));
  __syncthreads();
  float sum = 0.f;
  #pragma unroll
  for (int i = 0; i < 16; i++) { v[i] = __expf(v[i] - m); sum += v[i]; }
  sum = wave_sum(sum);
  if (lane == 0) red[wave] = sum;
  __syncthreads();
  sum = red[0] + red[1] + red[2] + red[3];
  float inv = 1.f / sum;
  #pragma unroll
  for (int i = 0; i < 16; i++) wp[t + 256*i] = v[i] * inv;
}

// ---------------- K3: tokens[b][s][c] = max_n W[b][s][n] * x_flat[b][c*N+n] ----------------
// grid 1024 (= B * C/8), block 256. Wave covers 1024 n via float4; acc[8 c][8 s] per lane.
__global__ __launch_bounds__(256) void k3_tokens(
    const float* __restrict__ x, const float* __restrict__ W, float* __restrict__ TOK)
{
  int b = blockIdx.x >> 6;
  int c0 = (blockIdx.x & 63) * 8;
  int t = threadIdx.x, wave = t >> 6, lane = t & 63;
  const float* Wb = W + (long)b*PERB;
  const float* xb = x + (long)b*Nc*Cc;
  float acc[8][8];
  #pragma unroll
  for (int cc = 0; cc < 8; cc++)
    #pragma unroll
    for (int s = 0; s < 8; s++) acc[cc][s] = -3.4e38f;
  int nbase = wave * 1024 + 4*lane;
  #pragma unroll
  for (int step = 0; step < 4; step++) {
    int n = nbase + step*256;
    float4 wv[8];
    #pragma unroll
    for (int s = 0; s < 8; s++) wv[s] = *(const float4*)(Wb + s*Nc + n);
    #pragma unroll
    for (int cc = 0; cc < 8; cc++) {
      float4 xv = *(const float4*)(xb + (c0+cc)*Nc + n);
      #pragma unroll
      for (int s = 0; s < 8; s++) {
        float p0 = wv[s].x * xv.x, p1 = wv[s].y * xv.y;
        float p2 = wv[s].z * xv.z, p3 = wv[s].w * xv.w;
        acc[cc][s] = fmaxf(acc[cc][s], fmaxf(fmaxf(p0, p1), fmaxf(p2, p3)));
      }
    }
  }
  #pragma unroll
  for (int o = 32; o; o >>= 1) {
    #pragma unroll
    for (int cc = 0; cc < 8; cc++)
      #pragma unroll
      for (int s = 0; s < 8; s++)
        acc[cc][s] = fmaxf(acc[cc][s], __shfl_xor(acc[cc][s], o, 64));
  }
  __shared__ float part[4][64];
  if (lane == 0) {
    #pragma unroll
    for (int cc = 0; cc < 8; cc++)
      #pragma unroll
      for (int s = 0; s < 8; s++) part[wave][cc*8+s] = acc[cc][s];
  }
  __syncthreads();
  if (t < 64) {
    float m = fmaxf(fmaxf(part[0][t], part[1][t]), fmaxf(part[2][t], part[3][t]));
    int cc = t >> 3, s = t & 7;
    TOK[b*4096 + s*Cc + c0 + cc] = m;
  }
}

// ---------------- K4a: QKV[b][s][j] = dot(tokens[b][s][:], w_qkv[j][:]) ----------------
// grid 768 (= B * 1536/32), block 256. lane = (jj<<3)|s like K1.
__global__ __launch_bounds__(256) void k4a_qkv(
    const float* __restrict__ TOK, const float* __restrict__ w_qkv, float* __restrict__ QKV)
{
  int b = blockIdx.x / 48;
  int j0 = (blockIdx.x % 48) * 32;
  __shared__ float tl[Sc*WP];
  int t = threadIdx.x;
  for (int i = t; i < Sc*Cc; i += 256) {
    int s = i >> 9, c = i & 511;
    tl[s*WP + c] = TOK[b*4096 + i];
  }
  __syncthreads();
  int wave = t >> 6, lane = t & 63;
  int s = lane & 7, jj = lane >> 3;
  int j = j0 + wave*8 + jj;
  const float* wr = w_qkv + (long)j * Cc;
  float acc = 0.f;
  #pragma unroll 4
  for (int c = 0; c < Cc; c += 8) {
    float4 w0 = *(const float4*)(wr + c);
    float4 w1 = *(const float4*)(wr + c + 4);
    float4 t0 = *(const float4*)&tl[s*WP + c];
    float4 t1 = *(const float4*)&tl[s*WP + c + 4];
    acc = fmaf(w0.x, t0.x, acc);
    acc = fmaf(w0.y, t0.y, acc);
    acc = fmaf(w0.z, t0.z, acc);
    acc = fmaf(w0.w, t0.w, acc);
    acc = fmaf(w1.x, t1.x, acc);
    acc = fmaf(w1.y, t1.y, acc);
    acc = fmaf(w1.z, t1.z, acc);
    acc = fmaf(w1.w, t1.w, acc);
  }
  QKV[b*12288 + s*1536 + j] = acc;
}

// ---------------- K4b: tiny attention (S=8) + cross mix -> ASP2[b][s][c] ----------------
// grid 16 (= B), block 256.
__global__ __launch_bounds__(256) void k4b_attn(
    const float* __restrict__ QKV, const float* __restrict__ w_cross, float* __restrict__ ASP2)
{
  int b = blockIdx.x, t = threadIdx.x;
  __shared__ float qkv[12288];
  __shared__ float attn[512];   // [h][i][j]
  __shared__ float asp[4096];   // [i][c]
  __shared__ float wc[64];
  for (int i = t*4; i < 12288; i += 1024)
    *(float4*)&qkv[i] = *(const float4*)&QKV[b*12288 + i];
  if (t < 64) wc[t] = w_cross[t];
  __syncthreads();
  for (int idx = t; idx < 512; idx += 256) {
    int h = idx >> 6, i = (idx >> 3) & 7, j = idx & 7;
    float sc = 0.f;
    #pragma unroll 8
    for (int d = 0; d < 64; d++)
      sc = fmaf(qkv[i*1536 + h*64 + d], qkv[j*1536 + 512 + h*64 + d], sc);
    attn[idx] = sc * 0.125f;
  }
  __syncthreads();
  if (t < 64) {
    int base = t * 8;  // row (h,i)
    float m = -3.4e38f;
    #pragma unroll
    for (int j = 0; j < 8; j++) m = fmaxf(m, attn[base+j]);
    float sum = 0.f;
    #pragma unroll
    for (int j = 0; j < 8; j++) { float e = __expf(attn[base+j] - m); attn[base+j] = e; sum += e; }
    float inv = 1.f / sum;
    #pragma unroll
    for (int j = 0; j < 8; j++) attn[base+j] *= inv;
  }
  __syncthreads();
  for (int idx = t; idx < 4096; idx += 256) {
    int i = idx >> 9, c = idx & 511, h = c >> 6;
    float a = 0.f;
    #pragma unroll
    for (int j = 0; j < 8; j++)
      a = fmaf(attn[h*64 + i*8 + j], qkv[j*1536 + 1024 + c], a);
    asp[idx] = a;
  }
  __syncthreads();
  for (int idx = t; idx < 4096; idx += 256) {
    int s = idx >> 9, c = idx & 511;
    float a = 0.f;
    #pragma unroll
    for (int j = 0; j < 8; j++)
      a = fmaf(wc[s*8 + j], asp[j*512 + c], a);
    ASP2[b*4096 + idx] = a;
  }
}

// ---------------- K5: out[b,n,c] = LN_c(sum_s sa[b,n,s]*ASP2[b,s,c]) + x[b,n,c] ----------------
// grid 2048 (= B * N/32), block 256 -> 4+ blocks/CU for latency hiding.
// Lane owns c in [8l, 8l+8); asp2 tile cached in regs; wave handles 8 rows.
__global__ __launch_bounds__(256) void k5_out(
    const float* __restrict__ SA, const float* __restrict__ ASP2,
    const float* __restrict__ x, const float* __restrict__ gamma,
    const float* __restrict__ beta, float* __restrict__ out)
{
  int b = blockIdx.x >> 7;
  int n0 = (blockIdx.x & 127) * 32;
  int t = threadIdx.x, wave = t >> 6, lane = t & 63;
  int c0 = lane * 8;
  float a2[8][8];
  #pragma unroll
  for (int s = 0; s < 8; s++) {
    float4 p0 = *(const float4*)(ASP2 + b*4096 + s*Cc + c0);
    float4 p1 = *(const float4*)(ASP2 + b*4096 + s*Cc + c0 + 4);
    a2[s][0]=p0.x; a2[s][1]=p0.y; a2[s][2]=p0.z; a2[s][3]=p0.w;
    a2[s][4]=p1.x; a2[s][5]=p1.y; a2[s][6]=p1.z; a2[s][7]=p1.w;
  }
  float g[8], be[8];
  {
    float4 g0 = *(const float4*)(gamma + c0);
    float4 g1 = *(const float4*)(gamma + c0 + 4);
    float4 b0 = *(const float4*)(beta + c0);
    float4 b1 = *(const float4*)(beta + c0 + 4);
    g[0]=g0.x; g[1]=g0.y; g[2]=g0.z; g[3]=g0.w;
    g[4]=g1.x; g[5]=g1.y; g[6]=g1.z; g[7]=g1.w;
    be[0]=b0.x; be[1]=b0.y; be[2]=b0.z; be[3]=b0.w;
    be[4]=b1.x; be[5]=b1.y; be[6]=b1.z; be[7]=b1.w;
  }
  __shared__ float salds[32*8];  // [n_local][s]
  if (t < 256) {
    int s = t >> 5, nl = t & 31;
    salds[nl*8 + s] = SA[(long)b*PERB + s*Nc + n0 + nl];
  }
  __syncthreads();
  const float inv512 = 1.f/512.f;
  #pragma unroll 2
  for (int nl = wave*8; nl < wave*8 + 8; nl++) {
    int n = n0 + nl;
    float sa8[8];
    #pragma unroll
    for (int s = 0; s < 8; s++) sa8[s] = salds[nl*8 + s];
    long row = (long)b*Nc + n;
    float4 x0 = *(const float4*)(x + row*Cc + c0);
    float4 x1 = *(const float4*)(x + row*Cc + c0 + 4);
    float o[8];
    #pragma unroll
    for (int i = 0; i < 8; i++) {
      float v = 0.f;
      #pragma unroll
      for (int s = 0; s < 8; s++) v = fmaf(sa8[s], a2[s][i], v);
      o[i] = v;
    }
    float sum = 0.f, sq = 0.f;
    #pragma unroll
    for (int i = 0; i < 8; i++) { sum += o[i]; sq = fmaf(o[i], o[i], sq); }
    #pragma unroll
    for (int off = 32; off; off >>= 1) {
      sum += __shfl_xor(sum, off, 64);
      sq  += __shfl_xor(sq,  off, 64);
    }
    float mu = sum * inv512;
    float var = sq * inv512 - mu*mu;
    float r = rsqrtf(var + 1e-5f);
    float xf[8];
    xf[0]=x0.x; xf[1]=x0.y; xf[2]=x0.z; xf[3]=x0.w;
    xf[4]=x1.x; xf[5]=x1.y; xf[6]=x1.z; xf[7]=x1.w;
    float4 o0, o1;
    o0.x = (o[0] - mu) * r * g[0] + be[0] + xf[0];
    o0.y = (o[1] - mu) * r * g[1] + be[1] + xf[1];
    o0.z = (o[2] - mu) * r * g[2] + be[2] + xf[2];
    o0.w = (o[3] - mu) * r * g[3] + be[3] + xf[3];
    o1.x = (o[4] - mu) * r * g[4] + be[4] + xf[4];
    o1.y = (o[5] - mu) * r * g[5] + be[5] + xf[5];
    o1.z = (o[6] - mu) * r * g[6] + be[6] + xf[6];
    o1.w = (o[7] - mu) * r * g[7] + be[7] + xf[7];
    *(float4*)(out + row*Cc + c0) = o0;
    *(float4*)(out + row*Cc + c0 + 4) = o1;
  }
}

extern "C" void kernel_launch(void* const* d_in, const int* in_sizes, int n_in,
                              void* d_out, int out_size, void* d_ws, size_t ws_size,
                              hipStream_t stream) {
  const float* x       = (const float*)d_in[0];
  const float* w_sum   = (const float*)d_in[1];
  const float* b_sum   = (const float*)d_in[2];
  const float* w_qkv   = (const float*)d_in[3];
  const float* w_cross = (const float*)d_in[4];
  const float* gamma   = (const float*)d_in[5];
  const float* beta    = (const float*)d_in[6];
  float* out = (float*)d_out;
  float* ws = (float*)d_ws;
  float* SA   = ws;                 // 524288 f32
  float* W    = ws + 524288;        // 524288 f32
  float* TOK  = ws + 1048576;       // 65536 f32
  float* QKV  = ws + 1114112;       // 196608 f32
  float* ASP2 = ws + 1310720;       // 65536 f32

  k1_space_attn<<<2048, 256, 0, stream>>>(x, w_sum, b_sum, SA);
  k2_softmax<<<128, 256, 0, stream>>>(SA, W);
  k3_tokens<<<1024, 256, 0, stream>>>(x, W, TOK);
  k4a_qkv<<<768, 256, 0, stream>>>(TOK, w_qkv, QKV);
  k4b_attn<<<16, 256, 0, stream>>>(QKV, w_cross, ASP2);
  k5_out<<<2048, 256, 0, stream>>>(SA, ASP2, x, gamma, beta, out);
}